// Round 5
// baseline (46.805 us; speedup 1.0000x reference)
//
#include <hip/hip_runtime.h>
#include <math.h>

#define BB 32
#define TT 2048
#define CC 128
#define EE 256
#define LL 512
#define TYY 128
#define PP 24
#define CHUNKS 16          // t-chunks per batch row -> 128 t's per block
#define KWAVES 4

// ws layout (floats):
//   pbuf  : [B*CHUNKS][2][P*C] = 512*6144 = 3145728   at 0
//   tpart : [B*CHUNKS][E]      = 131072               at 3145728
//   cbase : [B][P][C]          = 98304                at 3276800
#define WS_PBUF  0
#define WS_TPART 3145728
#define WS_CBASE 3276800

// ---------------------------------------------------------------------------
// K1: phase-bucket masked sum/count + fused sin-pool. NO atomics.
// grid = B*CHUNKS (512, 2 blocks/CU), block = 256 (4 waves).
// Wave w: channel-half h=w&1 (c = h*64+lane), t-half q=w>>1 (64 t's).
// Separate per-wave sum/cnt planes [P][64] -> bank = lane%32 (2-way, free),
// lane-exclusive cells -> race-free non-atomic RMW (in-order LDS per lane).
// Global loads: lane-coalesced dwords, 8-deep prefetch into registers.
// sin-pool (VALU) hides under the 64 MB compulsory X+M stream.
// ---------------------------------------------------------------------------
__global__ __launch_bounds__(256) void k_main(const float* __restrict__ ts,
                                              const float* __restrict__ X,
                                              const int*   __restrict__ M,
                                              const float* __restrict__ tw,
                                              const float* __restrict__ tb,
                                              float* __restrict__ pbuf,
                                              float* __restrict__ tpart) {
    __shared__ float s_ts[128];
    __shared__ float acc_s[KWAVES][PP * 64];
    __shared__ float acc_c[KWAVES][PP * 64];
    const int tid  = threadIdx.x;
    const int wave = tid >> 6;
    const int lane = tid & 63;
    const int blk  = blockIdx.x;
    const int b    = blk >> 4;
    const int chunk = blk & 15;

    if (tid < 128) s_ts[tid] = ts[b * TT + chunk * 128 + tid];
    {
        float* zs = &acc_s[0][0];
        float* zc = &acc_c[0][0];
        for (int i = tid; i < KWAVES * PP * 64; i += 256) { zs[i] = 0.0f; zc[i] = 0.0f; }
    }
    __syncthreads();

    const int h = wave & 1;
    const int q = wave >> 1;
    const int c = h * 64 + lane;
    const int tloc0 = q * 64;
    float* as = acc_s[wave];
    float* ac = acc_c[wave];

    for (int batch = 0; batch < 8; ++batch) {
        float xv[8], mv[8], tv[8];
#pragma unroll
        for (int k = 0; k < 8; ++k) {
            const int tl = tloc0 + batch * 8 + k;
            const long base = ((long)(b * TT + chunk * 128 + tl)) * CC + c;
            xv[k] = X[base];
            mv[k] = (float)M[base];
            tv[k] = s_ts[tl];
        }
#pragma unroll
        for (int k = 0; k < 8; ++k) {
            const int p = ((int)floorf(tv[k])) % PP;   // ts >= 0
            as[p * 64 + lane] += xv[k] * mv[k];
            ac[p * 64 + lane] += mv[k];
        }
    }

    // fused sin-pool: e = tid, over this chunk's 128 t's
    {
        const float w  = tw[tid];
        const float bb = tb[tid];
        float a = 0.0f;
#pragma unroll 8
        for (int j = 0; j < 128; ++j) {
            const float v = fmaf(s_ts[j], w, bb);
            a += v + __sinf(v);
        }
        tpart[blk * EE + tid] = a;
    }
    __syncthreads();

    // flush: combine the two t-halves per channel-half -> per-block partials
    float* pb = pbuf + (long)blk * 2 * (PP * CC);
    for (int i = tid; i < PP * CC; i += 256) {
        const int p  = i >> 7;
        const int cc = i & 127;
        const int hh = cc >> 6;
        const int ll = cc & 63;
        pb[i]           = acc_s[hh][p * 64 + ll] + acc_s[2 + hh][p * 64 + ll];
        pb[PP * CC + i] = acc_c[hh][p * 64 + ll] + acc_c[2 + hh][p * 64 + ll];
    }
}

// ---------------------------------------------------------------------------
// K2: reduce chunk partials -> c_base = sum / max(cnt,1).
// grid = B*P (768), block = 128 (c)
// ---------------------------------------------------------------------------
__global__ __launch_bounds__(128) void k_reduce(const float* __restrict__ pbuf,
                                                float* __restrict__ cbase) {
    const int b = blockIdx.x / PP;
    const int p = blockIdx.x % PP;
    const int c = threadIdx.x;
    const int pi = p * CC + c;
    float s = 0.0f, n = 0.0f;
#pragma unroll
    for (int k = 0; k < CHUNKS; ++k) {
        const float* pb = pbuf + (long)(b * CHUNKS + k) * 2 * (PP * CC);
        s += pb[pi];
        n += pb[PP * CC + pi];
    }
    cbase[(b * PP + p) * CC + c] = s / fmaxf(n, 1.0f);
}

// ---------------------------------------------------------------------------
// K3: decoder MLP + output scatter, per batch row. grid = B, block = 512.
// Y never leaves LDS; cbase slice staged to LDS; 16K coalesced out writes.
// ---------------------------------------------------------------------------
__global__ __launch_bounds__(512) void k_tail(const float* __restrict__ tpart,
                                              const float* __restrict__ ce,
                                              const float* __restrict__ w1,
                                              const float* __restrict__ b1,
                                              const float* __restrict__ w2,
                                              const float* __restrict__ b2,
                                              const float* __restrict__ cbase,
                                              const float* __restrict__ yt,
                                              float* __restrict__ out) {
    __shared__ float s_pool[EE];
    __shared__ float s_h[LL];
    __shared__ float s_part[512];
    __shared__ float s_cb[PP * CC];
    const int b = blockIdx.x;
    const int tid = threadIdx.x;

    // channel-embed column mean (e = tid&255, halves over c)
    {
        const int e = tid & 255;
        const int half = tid >> 8;
        float cm = 0.0f;
#pragma unroll 16
        for (int cc = half * 64; cc < half * 64 + 64; ++cc) cm += ce[cc * EE + e];
        s_part[tid] = cm;
    }
    __syncthreads();
    if (tid < EE) {
        float sp = 0.0f;
#pragma unroll
        for (int k = 0; k < CHUNKS; ++k) sp += tpart[(b * CHUNKS + k) * EE + tid];
        s_pool[tid] = sp * (1.0f / TT)
                    + (s_part[tid] + s_part[tid + 256]) * (1.0f / CC);
    }
    __syncthreads();

    float hacc = b1[tid];
#pragma unroll 16
    for (int e = 0; e < EE; ++e) hacc = fmaf(s_pool[e], w1[e * LL + tid], hacc);
    s_h[tid] = fmaxf(hacc, 0.0f);
    __syncthreads();

    {
        const int c = tid & 127;
        const int qq = tid >> 7;
        float y = 0.0f;
#pragma unroll 16
        for (int l = qq * 128; l < qq * 128 + 128; ++l) y = fmaf(s_h[l], w2[l * CC + c], y);
        s_part[tid] = y;
    }
    // stage this b's cbase slice (independent of the y-dot above)
    for (int i = tid; i < PP * CC; i += 512) s_cb[i] = cbase[b * PP * CC + i];
    __syncthreads();
    if (tid < CC)
        s_pool[tid] = b2[tid] + s_part[tid] + s_part[tid + 128]
                    + s_part[tid + 256] + s_part[tid + 384];   // Y row in LDS
    __syncthreads();

    for (int i = tid; i < TYY * CC; i += 512) {
        const int ty = i >> 7;
        const int c = i & 127;
        const float v = yt[b * TYY + ty];
        int p = ((int)floorf(v)) % PP; if (p < 0) p += PP;
        out[((long)(b * TYY + ty)) * CC + c] = s_pool[c] + s_cb[p * CC + c];
    }
}

extern "C" void kernel_launch(void* const* d_in, const int* in_sizes, int n_in,
                              void* d_out, int out_size, void* d_ws, size_t ws_size,
                              hipStream_t stream) {
    const float* ts   = (const float*)d_in[0];
    const float* X    = (const float*)d_in[1];
    const int*   M    = (const int*)  d_in[2];
    const float* yt   = (const float*)d_in[3];
    const float* tw   = (const float*)d_in[4];
    const float* tb   = (const float*)d_in[5];
    const float* ce   = (const float*)d_in[6];
    const float* w1   = (const float*)d_in[7];
    const float* b1   = (const float*)d_in[8];
    const float* w2   = (const float*)d_in[9];
    const float* b2   = (const float*)d_in[10];
    float* out = (float*)d_out;

    float* ws    = (float*)d_ws;
    float* pbuf  = ws + WS_PBUF;
    float* tpart = ws + WS_TPART;
    float* cbase = ws + WS_CBASE;

    k_main<<<BB * CHUNKS, 256, 0, stream>>>(ts, X, M, tw, tb, pbuf, tpart);
    k_reduce<<<BB * PP, 128, 0, stream>>>(pbuf, cbase);
    k_tail<<<BB, 512, 0, stream>>>(tpart, ce, w1, b1, w2, b2, cbase, yt, out);
}

// Round 6
// 37.853 us; speedup vs baseline: 1.2365x; 1.2365x over previous
//
#include <hip/hip_runtime.h>
#include <math.h>

#define BB 32
#define TT 2048
#define CC 128
#define EE 256
#define LL 512
#define TYY 128
#define PP 24
#define KS 8            // K-splits per batch row (blocks per b)
#define KT 256          // t's per block
#define NST 8           // stages per block (32 t each)
#define PITCH 40        // halfwords per W_lds row (80B: 16B-aligned, ~2-way banks)

// ws layout (floats):
//   pbuf  : [B*KS][P][256]   = 1572864  at 0        (j<128: sum, j>=128: cnt)
//   tpart : [B*KS*2][E]      = 131072   at 1572864
//   cbase : [B][P][C]        = 98304    at 1703936
#define WS_PBUF  0
#define WS_TPART 1572864
#define WS_CBASE 1703936

typedef __attribute__((ext_vector_type(8))) short bf16x8;
typedef __attribute__((ext_vector_type(4))) float f32x4;

__device__ __forceinline__ unsigned int pack_bf2(float a, float b) {
    unsigned int ua = __float_as_uint(a);
    unsigned int ub = __float_as_uint(b);
    ua = (ua + 0x7FFFu + ((ua >> 16) & 1u)) >> 16;           // RNE bf16 of a (low)
    ub = (ub + 0x7FFFu + ((ub >> 16) & 1u)) & 0xFFFF0000u;   // RNE bf16 of b (high)
    return ua | ub;
}

// ---------------------------------------------------------------------------
// K1: phase-bucket einsum via MFMA + fused sin-pool.
// grid = B*KS (256), block = 512 (8 waves).
// Per block: S[p 0..23][j 0..255] += onehot[p,t] * W[t,j] over its 256 t's,
// where W[t][j<128] = bf16(X*M), W[t][128+c] = bf16(M)  (counts via GEMM).
// A-fragment (one-hot) built in-register: lane m = lane&15 (+16*mt),
// k = (lane>>4)*8+e.  B read from LDS W[j][t] as one ds_read_b128.
// Wave w: mt = w&1 (p-halves), j-tiles (w>>1)*4..+3.
// ---------------------------------------------------------------------------
__global__ __launch_bounds__(512) void k_main(const float* __restrict__ ts,
                                              const float* __restrict__ X,
                                              const int*   __restrict__ M,
                                              const float* __restrict__ tw,
                                              const float* __restrict__ tbias,
                                              float* __restrict__ pbuf,
                                              float* __restrict__ tpart) {
    __shared__ unsigned short wbuf[256 * PITCH];   // 20 KB
    __shared__ float s_ts[KT];
    __shared__ int   s_p[KT];

    const int tid = threadIdx.x;
    const int blk = blockIdx.x;
    const int b   = blk >> 3;
    const int ks  = blk & 7;
    const int tB  = ks * KT;

    if (tid < KT) {
        const float v = ts[b * TT + tB + tid];
        s_ts[tid] = v;
        s_p[tid] = ((int)floorf(v)) % PP;          // ts >= 0
    }

    // staging roles
    const int jc = tid & 63;
    const int tp = tid >> 6;                       // 0..7 (== wave id)
    float xr[2][4]; int mr[2][4];

    // compute roles
    const int wv   = tid >> 6;
    const int lane = tid & 63;
    const int mt   = wv & 1;
    const int jt0  = (wv >> 1) * 4;
    const int mrow = mt * 16 + (lane & 15);
    const int kg   = lane >> 4;                    // 0..3
    const int k0   = kg * 8;
    const int n16  = lane & 15;

    // sin roles
    const int se = tid & 255;
    const int sh = tid >> 8;                       // 0/1 t-half
    const float sw = tw[se];
    const float sb = tbias[se];
    float sacc = 0.0f;

    f32x4 acc[4];
#pragma unroll
    for (int jl = 0; jl < 4; ++jl) acc[jl] = (f32x4){0.f, 0.f, 0.f, 0.f};

    auto LOADS = [&](int s) {
#pragma unroll
        for (int it = 0; it < 2; ++it) {
            const int ttv = it * 16 + tp * 2;
            const long r0 = ((long)(b * TT + tB + s * 32 + ttv)) * CC;
            xr[it][0] = X[r0 + jc];
            xr[it][1] = X[r0 + jc + 64];
            xr[it][2] = X[r0 + CC + jc];
            xr[it][3] = X[r0 + CC + jc + 64];
            mr[it][0] = M[r0 + jc];
            mr[it][1] = M[r0 + jc + 64];
            mr[it][2] = M[r0 + CC + jc];
            mr[it][3] = M[r0 + CC + jc + 64];
        }
    };

    auto WRITES = [&]() {
        unsigned int* wb = (unsigned int*)wbuf;
#pragma unroll
        for (int it = 0; it < 2; ++it) {
            const int ttv = it * 16 + tp * 2;
            const int th = ttv >> 1;               // u32 slot within row
            const float xm00 = mr[it][0] ? xr[it][0] : 0.0f;   // t even, c=jc
            const float xm10 = mr[it][2] ? xr[it][2] : 0.0f;   // t odd,  c=jc
            const float xm01 = mr[it][1] ? xr[it][1] : 0.0f;   // t even, c=jc+64
            const float xm11 = mr[it][3] ? xr[it][3] : 0.0f;   // t odd,  c=jc+64
            wb[jc * 20 + th]          = pack_bf2(xm00, xm10);
            wb[(jc + 64) * 20 + th]   = pack_bf2(xm01, xm11);
            wb[(128 + jc) * 20 + th]  = (mr[it][0] ? 0x3F80u : 0u) | (mr[it][2] ? 0x3F800000u : 0u);
            wb[(192 + jc) * 20 + th]  = (mr[it][1] ? 0x3F80u : 0u) | (mr[it][3] ? 0x3F800000u : 0u);
        }
    };

    auto COMPUTE = [&](int s) {
        union { unsigned int u[4]; bf16x8 v; } au;
        const int tb0 = s * 32 + k0;
        const int4 pA = *(const int4*)&s_p[tb0];
        const int4 pB = *(const int4*)&s_p[tb0 + 4];
        au.u[0] = (pA.x == mrow ? 0x3F80u : 0u) | (pA.y == mrow ? 0x3F800000u : 0u);
        au.u[1] = (pA.z == mrow ? 0x3F80u : 0u) | (pA.w == mrow ? 0x3F800000u : 0u);
        au.u[2] = (pB.x == mrow ? 0x3F80u : 0u) | (pB.y == mrow ? 0x3F800000u : 0u);
        au.u[3] = (pB.z == mrow ? 0x3F80u : 0u) | (pB.w == mrow ? 0x3F800000u : 0u);
#pragma unroll
        for (int jl = 0; jl < 4; ++jl) {
            const int jrow = (jt0 + jl) * 16 + n16;
            const bf16x8 bv = *(const bf16x8*)&wbuf[jrow * PITCH + k0];
            acc[jl] = __builtin_amdgcn_mfma_f32_16x16x32_bf16(au.v, bv, acc[jl], 0, 0, 0);
        }
    };

    auto SINC = [&](int s) {
#pragma unroll
        for (int j = 0; j < 16; ++j) {
            const float v = fmaf(s_ts[s * 32 + sh * 16 + j], sw, sb);
            sacc += v + __sinf(v);
        }
    };

    LOADS(0);
    __syncthreads();                               // covers s_ts/s_p init
    for (int s = 0; s < NST; ++s) {
        WRITES();
        if (s + 1 < NST) LOADS(s + 1);             // overlap HBM with compute(s)
        SINC(s);
        __syncthreads();
        COMPUTE(s);
        __syncthreads();
    }

    tpart[((b * KS + ks) * 2 + sh) * EE + se] = sacc;

    // flush accumulators: C/D layout col=lane&15, row=(lane>>4)*4+reg (verified)
    float* pbb = pbuf + ((long)(b * KS + ks)) * PP * 256;
#pragma unroll
    for (int jl = 0; jl < 4; ++jl) {
#pragma unroll
        for (int r = 0; r < 4; ++r) {
            const int p = mt * 16 + kg * 4 + r;
            if (p < PP)
                pbb[p * 256 + (jt0 + jl) * 16 + n16] = acc[jl][r];
        }
    }
}

// ---------------------------------------------------------------------------
// K2: reduce K-split partials -> c_base = sum / max(cnt,1).
// grid = B*P (768), block = 128 (c)
// ---------------------------------------------------------------------------
__global__ __launch_bounds__(128) void k_reduce(const float* __restrict__ pbuf,
                                                float* __restrict__ cbase) {
    const int b = blockIdx.x / PP;
    const int p = blockIdx.x % PP;
    const int c = threadIdx.x;
    float s = 0.0f, n = 0.0f;
#pragma unroll
    for (int k = 0; k < KS; ++k) {
        const float* pb = pbuf + ((long)(b * KS + k)) * PP * 256 + p * 256;
        s += pb[c];
        n += pb[128 + c];
    }
    cbase[(b * PP + p) * CC + c] = s / fmaxf(n, 1.0f);
}

// ---------------------------------------------------------------------------
// K3: decoder MLP + output scatter. grid = B*8 (256), block = 512.
// Each block redundantly computes pooled/h/Y for its b, writes 16 ty-rows.
// ---------------------------------------------------------------------------
__global__ __launch_bounds__(512) void k_tail(const float* __restrict__ tpart,
                                              const float* __restrict__ ce,
                                              const float* __restrict__ w1,
                                              const float* __restrict__ b1,
                                              const float* __restrict__ w2,
                                              const float* __restrict__ b2,
                                              const float* __restrict__ cbase,
                                              const float* __restrict__ yt,
                                              float* __restrict__ out) {
    __shared__ float s_pool[EE];
    __shared__ float s_h[LL];
    __shared__ float s_part[512];
    __shared__ float s_cb[PP * CC];
    __shared__ float s_y[CC];
    const int b = blockIdx.x >> 3;
    const int oct = blockIdx.x & 7;
    const int tid = threadIdx.x;

    // channel-embed column mean
    {
        const int e = tid & 255;
        const int half = tid >> 8;
        float cm = 0.0f;
#pragma unroll 16
        for (int cc = half * 64; cc < half * 64 + 64; ++cc) cm += ce[cc * EE + e];
        s_part[tid] = cm;
    }
    __syncthreads();
    if (tid < EE) {
        float sp = 0.0f;
#pragma unroll
        for (int k = 0; k < KS * 2; ++k) sp += tpart[(b * KS * 2 + k) * EE + tid];
        s_pool[tid] = sp * (1.0f / TT)
                    + (s_part[tid] + s_part[tid + 256]) * (1.0f / CC);
    }
    __syncthreads();

    float hacc = b1[tid];
#pragma unroll 16
    for (int e = 0; e < EE; ++e) hacc = fmaf(s_pool[e], w1[e * LL + tid], hacc);
    s_h[tid] = fmaxf(hacc, 0.0f);
    __syncthreads();

    {
        const int c = tid & 127;
        const int q = tid >> 7;
        float y = 0.0f;
#pragma unroll 16
        for (int l = q * 128; l < q * 128 + 128; ++l) y = fmaf(s_h[l], w2[l * CC + c], y);
        s_part[tid] = y;
    }
    for (int i = tid; i < PP * CC; i += 512) s_cb[i] = cbase[b * PP * CC + i];
    __syncthreads();
    if (tid < CC)
        s_y[tid] = b2[tid] + s_part[tid] + s_part[tid + 128]
                 + s_part[tid + 256] + s_part[tid + 384];
    __syncthreads();

    for (int i = tid; i < 16 * CC; i += 512) {
        const int ty = oct * 16 + (i >> 7);
        const int c = i & 127;
        const float v = yt[b * TYY + ty];
        int p = ((int)floorf(v)) % PP; if (p < 0) p += PP;
        out[((long)(b * TYY + ty)) * CC + c] = s_y[c] + s_cb[p * CC + c];
    }
}

extern "C" void kernel_launch(void* const* d_in, const int* in_sizes, int n_in,
                              void* d_out, int out_size, void* d_ws, size_t ws_size,
                              hipStream_t stream) {
    const float* ts   = (const float*)d_in[0];
    const float* X    = (const float*)d_in[1];
    const int*   M    = (const int*)  d_in[2];
    const float* yt   = (const float*)d_in[3];
    const float* tw   = (const float*)d_in[4];
    const float* tb   = (const float*)d_in[5];
    const float* ce   = (const float*)d_in[6];
    const float* w1   = (const float*)d_in[7];
    const float* b1   = (const float*)d_in[8];
    const float* w2   = (const float*)d_in[9];
    const float* b2   = (const float*)d_in[10];
    float* out = (float*)d_out;

    float* ws    = (float*)d_ws;
    float* pbuf  = ws + WS_PBUF;
    float* tpart = ws + WS_TPART;
    float* cbase = ws + WS_CBASE;

    k_main<<<BB * KS, 512, 0, stream>>>(ts, X, M, tw, tb, pbuf, tpart);
    k_reduce<<<BB * PP, 128, 0, stream>>>(pbuf, cbase);
    k_tail<<<BB * 8, 512, 0, stream>>>(tpart, ce, w1, b1, w2, b2, cbase, yt, out);
}